// Round 3
// baseline (346.657 us; speedup 1.0000x reference)
//
#include <hip/hip_runtime.h>

// SAGE mean-aggregation + linear:  out = (segment_sum(x[col], row) / (deg+eps)) @ W^T + b
// N=40000 nodes, E=640000 edges, F_IN=F_OUT=128, fp32.
//
// Pipeline (all on `stream`, ws ~2.9 MB):
//   memset  : zero deg[40000]                  (hipMemsetAsync — capture-safe)
//   k_count : deg[row[e]]++                    (640K int atomics)
//   k_scan  : exclusive prefix sum -> cursor   (single 1024-thread block)
//   k_fill  : csr[cursor[row[e]]++] = col[e]   (640K int atomics)
//   k_agg   : per-node pull: mean row -> d_out (wave/node, float4, half-wave/edge)
//   k_gemm  : in-place d_out = d_out @ W^T + b (W in LDS, rotation-swizzled)

constexpr int NN = 40000;
constexpr int NE = 640000;
constexpr float EPS = 1e-6f;

__global__ __launch_bounds__(256) void k_count(const int* __restrict__ row,
                                               int* __restrict__ deg) {
  int e = blockIdx.x * 256 + threadIdx.x;
  if (e < NE) atomicAdd(&deg[row[e]], 1);
}

// single-block exclusive scan of deg[0..NN) into cursor[0..NN)
__global__ __launch_bounds__(1024) void k_scan(const int* __restrict__ deg,
                                               int* __restrict__ cursor) {
  __shared__ int s[1024];
  const int t = threadIdx.x;
  constexpr int CH = 40;                 // 1024*40 = 40960 >= 40000
  const int base = t * CH;
  int sum = 0;
  for (int i = 0; i < CH; ++i) {
    int idx = base + i;
    if (idx < NN) sum += deg[idx];
  }
  s[t] = sum;
  __syncthreads();
  for (int off = 1; off < 1024; off <<= 1) {
    int v = (t >= off) ? s[t - off] : 0;
    __syncthreads();
    s[t] += v;
    __syncthreads();
  }
  int run = (t == 0) ? 0 : s[t - 1];
  for (int i = 0; i < CH; ++i) {
    int idx = base + i;
    if (idx < NN) { cursor[idx] = run; run += deg[idx]; }
  }
}

__global__ __launch_bounds__(256) void k_fill(const int* __restrict__ row,
                                              const int* __restrict__ col,
                                              int* __restrict__ cursor,
                                              int* __restrict__ csr) {
  int e = blockIdx.x * 256 + threadIdx.x;
  if (e < NE) {
    int pos = atomicAdd(&cursor[row[e]], 1);
    csr[pos] = col[e];
  }
}

// One wave per destination node. Lanes 0..31 handle even edges, 32..63 odd
// edges of the neighbor list; each half-wave loads a full 512B feature row as
// 32 x float4 (1 KiB per wave VMEM instruction). Up to 4 gathers in flight
// per half-wave (stride-8 over the edge list) to hide gather latency.
// Halves combined via shfl_xor; lanes 0..31 write the mean row.
__global__ __launch_bounds__(256) void k_agg(const float4* __restrict__ x4,
                                             const int* __restrict__ csr,
                                             const int* __restrict__ deg,
                                             const int* __restrict__ cursor,
                                             float4* __restrict__ out4) {
  const int wid  = threadIdx.x >> 6;
  const int lane = threadIdx.x & 63;
  const int half = lane >> 5;      // which edge of the pair
  const int fl   = lane & 31;      // float4 slot within the 128-float row
  const int n = blockIdx.x * 4 + wid;        // grid = 10000 -> exact
  const int end = cursor[n];                 // after k_fill: start + deg
  const int d = deg[n];
  const int start = end - d;
  float ax = 0.f, ay = 0.f, az = 0.f, aw = 0.f;
  // 8 edges per iteration (4 per half-wave) for gather-latency hiding
  for (int j = 0; j < d; j += 8) {
#pragma unroll
    for (int u = 0; u < 4; ++u) {
      int jj = j + 2 * u + half;
      if (jj < d) {
        int c = csr[start + jj];
        float4 v = x4[(size_t)c * 32 + fl];
        ax += v.x; ay += v.y; az += v.z; aw += v.w;
      }
    }
  }
  // combine the two half-wave partial sums (partner = lane ^ 32)
  ax += __shfl_xor(ax, 32);
  ay += __shfl_xor(ay, 32);
  az += __shfl_xor(az, 32);
  aw += __shfl_xor(aw, 32);
  const float sc = 1.0f / ((float)d + EPS);
  if (half == 0) {
    float4 o;
    o.x = ax * sc; o.y = ay * sc; o.z = az * sc; o.w = aw * sc;
    out4[(size_t)n * 32 + fl] = o;
  }
}

// In-place: out[n][:] = mean_row(out[n]) @ W^T + b.
// W staged to LDS transposed with rotation swizzle wt[k*128 + ((f+k)&127)],
// making both the transposing store and the per-k reads conflict-free (<=2-way).
// 4 waves/block, 4 nodes/wave, mean rows staged in per-wave LDS for broadcast.
__global__ __launch_bounds__(256, 2) void k_gemm(const float* __restrict__ W,
                                                 const float* __restrict__ b,
                                                 float* __restrict__ out) {
  __shared__ float wt[128 * 128];     // 64 KiB, swizzled W^T
  __shared__ float ms[4][4][128];     // 8 KiB: [wave][node][k]
  const int tid = threadIdx.x;
  for (int a = tid; a < 128 * 128; a += 256) {
    int f = a >> 7;                   // W is [f][k], row-major -> coalesced read
    int k = a & 127;
    wt[k * 128 + ((f + k) & 127)] = W[a];
  }
  const int wid  = tid >> 6;
  const int lane = tid & 63;
  const int base = blockIdx.x * 16 + wid * 4;   // grid = 2500 -> exact
  // read this wave's 4 mean rows BEFORE overwriting them later
  const float2* o2 = (const float2*)out;
  float2 mrow[4];
#pragma unroll
  for (int m = 0; m < 4; ++m)
    mrow[m] = o2[(size_t)(base + m) * 64 + lane];
  __syncthreads();                    // wt ready
#pragma unroll
  for (int m = 0; m < 4; ++m)
    *(float2*)&ms[wid][m][2 * lane] = mrow[m];
  __syncthreads();                    // ms visible (cheap, safe)
  float acc0[4] = {0.f, 0.f, 0.f, 0.f};
  float acc1[4] = {0.f, 0.f, 0.f, 0.f};
#pragma unroll 4
  for (int k = 0; k < 128; ++k) {
    float w0 = wt[k * 128 + ((lane + k) & 127)];        // f = lane
    float w1 = wt[k * 128 + ((lane + 64 + k) & 127)];   // f = lane + 64
#pragma unroll
    for (int m = 0; m < 4; ++m) {
      float mk = ms[wid][m][k];       // broadcast read
      acc0[m] += mk * w0;
      acc1[m] += mk * w1;
    }
  }
  const float b0 = b[lane];
  const float b1 = b[lane + 64];
#pragma unroll
  for (int m = 0; m < 4; ++m) {
    out[(size_t)(base + m) * 128 + lane]      = acc0[m] + b0;
    out[(size_t)(base + m) * 128 + lane + 64] = acc1[m] + b1;
  }
}

extern "C" void kernel_launch(void* const* d_in, const int* in_sizes, int n_in,
                              void* d_out, int out_size, void* d_ws, size_t ws_size,
                              hipStream_t stream) {
  const float* x   = (const float*)d_in[0];
  const int*   row = (const int*)d_in[1];
  const int*   col = (const int*)d_in[2];
  const float* W   = (const float*)d_in[3];
  const float* b   = (const float*)d_in[4];
  float* out = (float*)d_out;

  char* ws = (char*)d_ws;
  int* deg    = (int*)(ws + 0);        // 160000 B
  int* cursor = (int*)(ws + 163840);   // 160000 B
  int* csr    = (int*)(ws + 327680);   // 2560000 B  -> total ~2.89 MB

  hipMemsetAsync(deg, 0, NN * sizeof(int), stream);
  k_count<<<NE / 256,  256, 0, stream>>>(row, deg);
  k_scan <<<1,        1024, 0, stream>>>(deg, cursor);
  k_fill <<<NE / 256,  256, 0, stream>>>(row, col, cursor, csr);
  k_agg  <<<NN / 4,    256, 0, stream>>>((const float4*)x, csr, deg, cursor,
                                         (float4*)out);
  k_gemm <<<NN / 16,   256, 0, stream>>>(W, b, out);
}

// Round 4
// 327.124 us; speedup vs baseline: 1.0597x; 1.0597x over previous
//
#include <hip/hip_runtime.h>

// SAGE mean-aggregation + linear:  out = (segment_sum(x[col], row) / (deg+eps)) @ W^T + b
// N=40000 nodes, E=640000 edges, F_IN=F_OUT=128, fp32.
//
// Pipeline (all on `stream`, ws ~2.9 MB):
//   memset  : zero deg[40000]                  (hipMemsetAsync — capture-safe)
//   k_count : deg[row[e]]++                    (640K int atomics)
//   k_scan  : exclusive prefix sum -> cursor   (single 1024-thread block)
//   k_fill  : csr[cursor[row[e]]++] = col[e]   (640K int atomics)
//   k_agg   : per-node pull: mean row -> d_out (wave/node, float4, half-wave/edge)
//   k_gemm  : in-place d_out = d_out @ W^T + b
//
// R3 post-mortem: k_gemm was 108us (VALUBusy 43%) — 6 scalar LDS reads per
// 8 FMAs. R4: 8 nodes/wave + k-unroll-4 + b128 broadcast m-reads
// -> 16 LDS ops per 64 FMAs. Predicted k_gemm ~15-25us.

constexpr int NN = 40000;
constexpr int NE = 640000;
constexpr float EPS = 1e-6f;

__global__ __launch_bounds__(256) void k_count(const int* __restrict__ row,
                                               int* __restrict__ deg) {
  int e = blockIdx.x * 256 + threadIdx.x;
  if (e < NE) atomicAdd(&deg[row[e]], 1);
}

// single-block exclusive scan of deg[0..NN) into cursor[0..NN)
__global__ __launch_bounds__(1024) void k_scan(const int* __restrict__ deg,
                                               int* __restrict__ cursor) {
  __shared__ int s[1024];
  const int t = threadIdx.x;
  constexpr int CH = 40;                 // 1024*40 = 40960 >= 40000
  const int base = t * CH;
  int sum = 0;
  for (int i = 0; i < CH; ++i) {
    int idx = base + i;
    if (idx < NN) sum += deg[idx];
  }
  s[t] = sum;
  __syncthreads();
  for (int off = 1; off < 1024; off <<= 1) {
    int v = (t >= off) ? s[t - off] : 0;
    __syncthreads();
    s[t] += v;
    __syncthreads();
  }
  int run = (t == 0) ? 0 : s[t - 1];
  for (int i = 0; i < CH; ++i) {
    int idx = base + i;
    if (idx < NN) { cursor[idx] = run; run += deg[idx]; }
  }
}

__global__ __launch_bounds__(256) void k_fill(const int* __restrict__ row,
                                              const int* __restrict__ col,
                                              int* __restrict__ cursor,
                                              int* __restrict__ csr) {
  int e = blockIdx.x * 256 + threadIdx.x;
  if (e < NE) {
    int pos = atomicAdd(&cursor[row[e]], 1);
    csr[pos] = col[e];
  }
}

// One wave per destination node. Half-wave per edge, float4 row loads
// (1 KiB per wave VMEM op), 4 gathers in flight per half-wave.
__global__ __launch_bounds__(256) void k_agg(const float4* __restrict__ x4,
                                             const int* __restrict__ csr,
                                             const int* __restrict__ deg,
                                             const int* __restrict__ cursor,
                                             float4* __restrict__ out4) {
  const int wid  = threadIdx.x >> 6;
  const int lane = threadIdx.x & 63;
  const int half = lane >> 5;      // which edge of the pair
  const int fl   = lane & 31;      // float4 slot within the 128-float row
  const int n = blockIdx.x * 4 + wid;        // grid = 10000 -> exact
  const int end = cursor[n];                 // after k_fill: start + deg
  const int d = deg[n];
  const int start = end - d;
  float ax = 0.f, ay = 0.f, az = 0.f, aw = 0.f;
  for (int j = 0; j < d; j += 8) {
#pragma unroll
    for (int u = 0; u < 4; ++u) {
      int jj = j + 2 * u + half;
      if (jj < d) {
        int c = csr[start + jj];
        float4 v = x4[(size_t)c * 32 + fl];
        ax += v.x; ay += v.y; az += v.z; aw += v.w;
      }
    }
  }
  ax += __shfl_xor(ax, 32);
  ay += __shfl_xor(ay, 32);
  az += __shfl_xor(az, 32);
  aw += __shfl_xor(aw, 32);
  const float sc = 1.0f / ((float)d + EPS);
  if (half == 0) {
    float4 o;
    o.x = ax * sc; o.y = ay * sc; o.z = az * sc; o.w = aw * sc;
    out4[(size_t)n * 32 + fl] = o;
  }
}

// In-place: out[n][:] = mean_row(out[n]) @ W^T + b.
// W staged to LDS transposed with rotation swizzle wt[k*128 + ((f+k)&127)]
// (store and per-k reads both conflict-free; confirmed 0 bank conflicts in R3).
// 4 waves/block, 8 nodes/wave; mean rows in per-wave LDS, read as b128
// broadcasts with k unrolled by 4: 16 LDS ops per 64 FMAs per thread.
__global__ __launch_bounds__(256, 2) void k_gemm(const float* __restrict__ W,
                                                 const float* __restrict__ b,
                                                 float* __restrict__ out) {
  __shared__ float wt[128 * 128];     // 64 KiB, swizzled W^T
  __shared__ float ms[4][8][128];     // 16 KiB: [wave][node][k]
  const int tid = threadIdx.x;
  for (int a = tid; a < 128 * 128; a += 256) {
    int f = a >> 7;                   // W is [f][k], row-major -> coalesced read
    int k = a & 127;
    wt[k * 128 + ((f + k) & 127)] = W[a];
  }
  const int wid  = tid >> 6;
  const int lane = tid & 63;
  const int base = blockIdx.x * 32 + wid * 8;   // grid = 1250 -> exact
  // wave reads its 8 mean rows (in-place source) before overwriting them:
  // lane -> row (lane>>3), 16 consecutive floats at col (lane&7)*16.
  {
    const int r  = lane >> 3;
    const int c0 = (lane & 7) * 16;
    const float4* o4 = (const float4*)(out + (size_t)(base + r) * 128 + c0);
    float4 m0 = o4[0], m1 = o4[1], m2 = o4[2], m3 = o4[3];
    float4* msp = (float4*)&ms[wid][r][c0];
    msp[0] = m0; msp[1] = m1; msp[2] = m2; msp[3] = m3;
  }
  __syncthreads();                    // wt + ms ready
  float acc0[8] = {0.f, 0.f, 0.f, 0.f, 0.f, 0.f, 0.f, 0.f};
  float acc1[8] = {0.f, 0.f, 0.f, 0.f, 0.f, 0.f, 0.f, 0.f};
  for (int k4 = 0; k4 < 32; ++k4) {
    const int k = k4 * 4;
    const float w00 = wt[(k + 0) * 128 + ((lane + k + 0) & 127)];
    const float w01 = wt[(k + 1) * 128 + ((lane + k + 1) & 127)];
    const float w02 = wt[(k + 2) * 128 + ((lane + k + 2) & 127)];
    const float w03 = wt[(k + 3) * 128 + ((lane + k + 3) & 127)];
    const float w10 = wt[(k + 0) * 128 + ((lane + 64 + k + 0) & 127)];
    const float w11 = wt[(k + 1) * 128 + ((lane + 64 + k + 1) & 127)];
    const float w12 = wt[(k + 2) * 128 + ((lane + 64 + k + 2) & 127)];
    const float w13 = wt[(k + 3) * 128 + ((lane + 64 + k + 3) & 127)];
#pragma unroll
    for (int m = 0; m < 8; ++m) {
      const float4 mm = *(const float4*)&ms[wid][m][k];   // broadcast b128
      acc0[m] += mm.x * w00 + mm.y * w01 + mm.z * w02 + mm.w * w03;
      acc1[m] += mm.x * w10 + mm.y * w11 + mm.z * w12 + mm.w * w13;
    }
  }
  const float b0 = b[lane];
  const float b1 = b[lane + 64];
#pragma unroll
  for (int m = 0; m < 8; ++m) {
    out[(size_t)(base + m) * 128 + lane]      = acc0[m] + b0;
    out[(size_t)(base + m) * 128 + lane + 64] = acc1[m] + b1;
  }
}

extern "C" void kernel_launch(void* const* d_in, const int* in_sizes, int n_in,
                              void* d_out, int out_size, void* d_ws, size_t ws_size,
                              hipStream_t stream) {
  const float* x   = (const float*)d_in[0];
  const int*   row = (const int*)d_in[1];
  const int*   col = (const int*)d_in[2];
  const float* W   = (const float*)d_in[3];
  const float* b   = (const float*)d_in[4];
  float* out = (float*)d_out;

  char* ws = (char*)d_ws;
  int* deg    = (int*)(ws + 0);        // 160000 B
  int* cursor = (int*)(ws + 163840);   // 160000 B
  int* csr    = (int*)(ws + 327680);   // 2560000 B  -> total ~2.89 MB

  hipMemsetAsync(deg, 0, NN * sizeof(int), stream);
  k_count<<<NE / 256,  256, 0, stream>>>(row, deg);
  k_scan <<<1,        1024, 0, stream>>>(deg, cursor);
  k_fill <<<NE / 256,  256, 0, stream>>>(row, col, cursor, csr);
  k_agg  <<<NN / 4,    256, 0, stream>>>((const float4*)x, csr, deg, cursor,
                                         (float4*)out);
  k_gemm <<<NN / 32,   256, 0, stream>>>(W, b, out);
}